// Round 1
// baseline (402.154 us; speedup 1.0000x reference)
//
#include <hip/hip_runtime.h>
#include <math.h>

#define BB 64
#define SS 2048
#define DD 512
#define CH 16
#define ROWS (SS/CH)   // 128 rows per chunk, 32 per wave

// ---------------- kernel 1: w[b,d] = (concat(c1,q)[b,:] . W_d2d[d,:] + b_d[d]) * W_1d[d]
__global__ __launch_bounds__(128) void k_w(
    const float* __restrict__ c1, const float* __restrict__ q,
    const float* __restrict__ Wd, const float* __restrict__ bd,
    const float* __restrict__ W1, float* __restrict__ w)
{
    __shared__ float conc[2*DD];
    const int b = blockIdx.y;
    const int t = threadIdx.x;
    for (int i = t; i < DD; i += 128) {
        conc[i]      = c1[b*DD + i];
        conc[DD + i] = q[b*DD + i];
    }
    __syncthreads();
    const int d = blockIdx.x * 128 + t;
    const float4* Wr = (const float4*)(Wd + (size_t)d * (2*DD));
    const float4* cc = (const float4*)conc;
    float acc = 0.f;
    #pragma unroll 8
    for (int k = 0; k < (2*DD)/4; ++k) {
        float4 a = Wr[k];
        float4 c = cc[k];
        acc += a.x*c.x + a.y*c.y + a.z*c.z + a.w*c.w;
    }
    w[b*DD + d] = (acc + bd[d]) * W1[d];
}

// ---------------- kernel 2: online-softmax partial over a chunk of 128 rows
__global__ __launch_bounds__(256) void k_pass(
    const float* __restrict__ cw, const float* __restrict__ w,
    float* __restrict__ pm, float* __restrict__ pl, float* __restrict__ pacc)
{
    const int blk  = blockIdx.x;
    const int b    = blk >> 4;        // /CH
    const int ch   = blk & (CH - 1);
    const int tid  = threadIdx.x;
    const int wave = tid >> 6;
    const int lane = tid & 63;

    // per-lane slice of w: d = lane*4 .. +3  and  256+lane*4 .. +3
    const float4* wb = (const float4*)(w + b*DD);
    const float4 w0 = wb[lane];
    const float4 w1 = wb[64 + lane];

    // this wave's first row; row stride within wave = 4 rows
    const float* rb = cw + ((size_t)b*SS + (size_t)ch*ROWS + wave) * DD;
    float4 r0 = ((const float4*)rb)[lane];
    float4 r1 = ((const float4*)rb)[64 + lane];

    float m = -INFINITY, l = 0.f;
    float4 a0 = make_float4(0,0,0,0), a1 = make_float4(0,0,0,0);

    #pragma unroll 2
    for (int i = 0; i < ROWS/4; ++i) {
        // prefetch next row (clamped on last iter to stay in-bounds)
        const int nx = (i < ROWS/4 - 1) ? (i + 1) : i;
        const float4* nb = (const float4*)(rb + (size_t)nx * 4 * DD);
        float4 n0 = nb[lane];
        float4 n1 = nb[64 + lane];

        float dot = r0.x*w0.x + r0.y*w0.y + r0.z*w0.z + r0.w*w0.w
                  + r1.x*w1.x + r1.y*w1.y + r1.z*w1.z + r1.w*w1.w;
        #pragma unroll
        for (int off = 32; off; off >>= 1) dot += __shfl_xor(dot, off, 64);

        if (dot > m) {              // wave-uniform branch
            float alpha = __expf(m - dot);   // first iter: expf(-inf)=0
            m = dot;
            l = l*alpha + 1.f;
            a0.x = a0.x*alpha + r0.x; a0.y = a0.y*alpha + r0.y;
            a0.z = a0.z*alpha + r0.z; a0.w = a0.w*alpha + r0.w;
            a1.x = a1.x*alpha + r1.x; a1.y = a1.y*alpha + r1.y;
            a1.z = a1.z*alpha + r1.z; a1.w = a1.w*alpha + r1.w;
        } else {
            float p = __expf(dot - m);
            l += p;
            a0.x += p*r0.x; a0.y += p*r0.y; a0.z += p*r0.z; a0.w += p*r0.w;
            a1.x += p*r1.x; a1.y += p*r1.y; a1.z += p*r1.z; a1.w += p*r1.w;
        }
        r0 = n0; r1 = n1;
    }

    // combine 4 waves within the block
    __shared__ float lm[4], ll[4];
    __shared__ float lacc[4][DD];
    if (lane == 0) lm[wave] = m;
    __syncthreads();
    const float M = fmaxf(fmaxf(lm[0], lm[1]), fmaxf(lm[2], lm[3]));
    const float beta = __expf(m - M);
    float4* lw = (float4*)lacc[wave];
    lw[lane]      = make_float4(a0.x*beta, a0.y*beta, a0.z*beta, a0.w*beta);
    lw[64 + lane] = make_float4(a1.x*beta, a1.y*beta, a1.z*beta, a1.w*beta);
    if (lane == 0) ll[wave] = l * beta;
    __syncthreads();
    const float s0 = lacc[0][tid]     + lacc[1][tid]     + lacc[2][tid]     + lacc[3][tid];
    const float s1 = lacc[0][tid+256] + lacc[1][tid+256] + lacc[2][tid+256] + lacc[3][tid+256];
    pacc[(size_t)blk*DD + tid]       = s0;
    pacc[(size_t)blk*DD + tid + 256] = s1;
    if (tid == 0) {
        pm[blk] = M;
        pl[blk] = ll[0] + ll[1] + ll[2] + ll[3];
    }
}

// ---------------- kernel 3: merge 16 chunk-partials per batch
__global__ __launch_bounds__(256) void k_comb(
    const float* __restrict__ pm, const float* __restrict__ pl,
    const float* __restrict__ pacc, float* __restrict__ out)
{
    const int b = blockIdx.x;
    const int tid = threadIdx.x;
    float M = -INFINITY;
    #pragma unroll
    for (int p = 0; p < CH; ++p) M = fmaxf(M, pm[b*CH + p]);
    float L = 0.f, s0 = 0.f, s1 = 0.f;
    #pragma unroll
    for (int p = 0; p < CH; ++p) {
        const float sc = __expf(pm[b*CH + p] - M);
        L  += pl[b*CH + p] * sc;
        s0 += sc * pacc[(size_t)(b*CH + p)*DD + tid];
        s1 += sc * pacc[(size_t)(b*CH + p)*DD + tid + 256];
    }
    out[b*DD + tid]       = s0 / L;
    out[b*DD + tid + 256] = s1 / L;
}

extern "C" void kernel_launch(void* const* d_in, const int* in_sizes, int n_in,
                              void* d_out, int out_size, void* d_ws, size_t ws_size,
                              hipStream_t stream)
{
    const float* c1 = (const float*)d_in[0];   // c_i_1 [B,D]
    const float* q  = (const float*)d_in[1];   // q     [B,D]
    const float* cw = (const float*)d_in[2];   // cw_s  [B,S,D]
    const float* Wd = (const float*)d_in[3];   // W_d2d [D,2D]
    const float* bd = (const float*)d_in[4];   // b_d   [D]
    const float* W1 = (const float*)d_in[5];   // W_1d  [1,D]
    // d_in[6] = b_1: constant logit shift -> cancels in softmax, unused.

    float* out  = (float*)d_out;
    float* ws   = (float*)d_ws;
    float* w    = ws;                    // B*D          = 32768 floats
    float* pm   = w  + BB*DD;            // B*CH         = 1024
    float* pl   = pm + BB*CH;            // B*CH         = 1024
    float* pacc = pl + BB*CH;            // B*CH*D       = 524288

    k_w   <<<dim3(DD/128, BB), 128, 0, stream>>>(c1, q, Wd, bd, W1, w);
    k_pass<<<BB*CH,            256, 0, stream>>>(cw, w, pm, pl, pacc);
    k_comb<<<BB,               256, 0, stream>>>(pm, pl, pacc, out);
}